// Round 2
// baseline (13116.655 us; speedup 1.0000x reference)
//
#include <hip/hip_runtime.h>
#include <hip/hip_bf16.h>
#include <cstddef>

#define B_ 8
#define T_ 256
#define N_ 32
#define D_ 128
#define S_ 8
#define V_ 32000
#define NCHUNK 32
#define CH_ 8
#define NBLK 64
#define STP 132   // stS row stride (pad: (kq*4+d)%32 distinct -> conflict-free)
#define KSP 133   // attn K/V row pad (5m mod 32 distinct)

__device__ __forceinline__ float gelu_f(float x){
    return 0.5f * x * (1.0f + erff(x * 0.70710678118654752440f));
}
__device__ __forceinline__ float sigm(float x){
    return 1.0f / (1.0f + expf(-x));
}

// ---------------- device-scope grid barrier (64 co-resident blocks) ----------------
__device__ __forceinline__ void gbar(unsigned* bar){
    __syncthreads();
    if (threadIdx.x == 0){
        unsigned* cnt = bar;
        unsigned* gen = bar + 1;
        unsigned g = __hip_atomic_load(gen, __ATOMIC_RELAXED, __HIP_MEMORY_SCOPE_AGENT);
        unsigned old = __hip_atomic_fetch_add(cnt, 1u, __ATOMIC_ACQ_REL, __HIP_MEMORY_SCOPE_AGENT);
        if (old == (unsigned)(NBLK - 1)){
            __hip_atomic_store(cnt, 0u, __ATOMIC_RELAXED, __HIP_MEMORY_SCOPE_AGENT);
            __hip_atomic_fetch_add(gen, 1u, __ATOMIC_RELEASE, __HIP_MEMORY_SCOPE_AGENT);
        } else {
            while (__hip_atomic_load(gen, __ATOMIC_ACQUIRE, __HIP_MEMORY_SCOPE_AGENT) == g)
                __builtin_amdgcn_s_sleep(8);
        }
    }
    __syncthreads();
}

// -------------------- percepts = LN(gelu(raw @ ifc_w + b)) --------------------
__global__ void k_percepts(const int* __restrict__ idx, const float* __restrict__ emb,
                           const float* __restrict__ pos_emb, const float* __restrict__ ifc_w,
                           const float* __restrict__ ifc_b, const float* __restrict__ ifc_g,
                           const float* __restrict__ ifc_beta, float* __restrict__ percepts){
    int r = blockIdx.x;          // r = b*T + t
    int t = r % T_;
    int d = threadIdx.x;         // 128 threads
    __shared__ float raw[D_];
    __shared__ float red[D_];
    int tok = idx[r];
    raw[d] = emb[tok*D_ + d] + pos_emb[t*D_ + d];
    __syncthreads();
    float acc = ifc_b[d];
    #pragma unroll 8
    for (int k=0;k<D_;k++) acc += raw[k]*ifc_w[k*D_+d];
    float x = gelu_f(acc);
    red[d] = x; __syncthreads();
    for (int s=64;s>0;s>>=1){ if(d<s) red[d]+=red[d+s]; __syncthreads(); }
    float m = red[0]*(1.0f/D_); __syncthreads();
    float dv = x-m; red[d] = dv*dv; __syncthreads();
    for (int s=64;s>0;s>>=1){ if(d<s) red[d]+=red[d+s]; __syncthreads(); }
    float var = red[0]*(1.0f/D_);
    percepts[r*D_ + d] = dv * (1.0f/sqrtf(var + 1e-5f)) * ifc_g[d] + ifc_beta[d];
}

// ------ hoisted precompute: sensory, sgate-sensory-part, residual->out contribution ------
__global__ void __launch_bounds__(256) k_precomp(const float* __restrict__ percepts,
                          const float* __restrict__ sproj_w, const float* __restrict__ sproj_b,
                          const float* __restrict__ sgate_w,
                          const float* __restrict__ res_w, const float* __restrict__ res_b,
                          const float* __restrict__ out_w,
                          float* __restrict__ sensory, float* __restrict__ sg_sens,
                          float* __restrict__ outres){
    int blk = blockIdx.x;     // 256: b*32 + c
    int b = blk >> 5, c = blk & 31;
    int tid = threadIdx.x;    // 256
    __shared__ float p[CH_][D_];
    __shared__ float sens[CH_][S_*D_];
    __shared__ float resid[CH_][D_];
    int tbase = b*T_ + c*CH_;
    for (int i = tid; i < CH_*D_; i += 256) p[i>>7][i&127] = percepts[(tbase + (i>>7))*D_ + (i&127)];
    __syncthreads();
    for (int q=0;q<4;q++){
        int sd = tid + 256*q;
        float acc[CH_];
        #pragma unroll
        for(int i=0;i<CH_;i++) acc[i] = sproj_b[sd];
        for (int k=0;k<D_;k++){
            float w = sproj_w[k*(S_*D_) + sd];
            #pragma unroll
            for(int i=0;i<CH_;i++) acc[i] += p[i][k]*w;
        }
        #pragma unroll
        for(int i=0;i<CH_;i++){
            sens[i][sd] = acc[i];
            sensory[(size_t)(tbase+i)*(S_*D_) + sd] = acc[i];
        }
    }
    __syncthreads();
    {
        int d = tid & 127, h = tid >> 7;   // h: i-half
        float acc[4][S_];
        #pragma unroll
        for(int ii=0;ii<4;ii++)
            #pragma unroll
            for(int s=0;s<S_;s++) acc[ii][s]=0.f;
        for (int k=0;k<D_;k++){
            float w = sgate_w[(D_+k)*D_ + d];
            #pragma unroll
            for(int ii=0;ii<4;ii++){
                int i = h*4+ii;
                #pragma unroll
                for(int s=0;s<S_;s++) acc[ii][s] += sens[i][s*D_+k]*w;
            }
        }
        for(int ii=0;ii<4;ii++){ int i=h*4+ii;
            for(int s=0;s<S_;s++) sg_sens[((size_t)(tbase+i)*S_+s)*D_ + d] = acc[ii][s];
        }
    }
    __syncthreads();
    {
        int d = tid & 127, h = tid>>7;
        float acc[4];
        #pragma unroll
        for(int ii=0;ii<4;ii++) acc[ii]=res_b[d];
        for(int k=0;k<D_;k++){
            float w = res_w[k*D_+d];
            #pragma unroll
            for(int ii=0;ii<4;ii++) acc[ii] += p[h*4+ii][k]*w;
        }
        for(int ii=0;ii<4;ii++) resid[h*4+ii][d]=acc[ii];
    }
    __syncthreads();
    {
        int d = tid & 127, h = tid>>7;
        float acc[4];
        #pragma unroll
        for(int ii=0;ii<4;ii++) acc[ii]=0.f;
        for(int k=0;k<D_;k++){
            float w = out_w[(D_+k)*D_ + d];
            #pragma unroll
            for(int ii=0;ii<4;ii++) acc[ii] += resid[h*4+ii][k]*w;
        }
        for(int ii=0;ii<4;ii++) outres[(size_t)(tbase+h*4+ii)*D_ + d] = acc[ii];
    }
}

// ---- transpose first-128 rows of sgate_w and out_w for register-cached scan GEMVs ----
__global__ void k_transp(const float* __restrict__ sgate_w, const float* __restrict__ out_w,
                         float* __restrict__ sgwT, float* __restrict__ outT){
    int k = blockIdx.x;    // 128
    int d = threadIdx.x;   // 128
    sgwT[d*D_ + k] = sgate_w[k*D_ + d];
    outT[d*D_ + k] = out_w[k*D_ + d];
}

// -------------------- persistent fused chunk-loop kernel --------------------
struct ScanSh {
    float stS[N_*STP];
    float wsp[D_];
    float U[D_];
    float esv[8];
    float salp[16*8];
    float sfp[16*24];
    float efx[24];
    float bcd[D_];
    float ffix, Kf5, Zf;
};
struct QkvSh { float srow[4][D_]; float part[4][2][D_]; };
struct AttnSh { float Kt[N_*KSP]; float Vt[N_*KSP]; float q[4][D_]; float attw[4][4][32];
                float msg[4][D_]; float part[4][2][D_]; float red[4][4]; };
struct BrainSh { float pin[4][3*D_]; float strow[4][D_]; float part[4][2][D_];
                 float din[4][2*D_]; float gin[4][2*D_]; float dec[4][D_]; float red[4][256]; };
union SwarmSh { ScanSh s; QkvSh q; AttnSh a; BrainSh b; };

__global__ void __launch_bounds__(1024, 4) k_swarm(
    unsigned* __restrict__ bar,
    const float* __restrict__ sensory, const float* __restrict__ sg_sens,
    const float* __restrict__ sgwT, const float* __restrict__ outT,
    const float* __restrict__ sgate_b, const float* __restrict__ sal_w, const float* __restrict__ sal_b,
    const float* __restrict__ out_b, const float* __restrict__ outres,
    const float* __restrict__ bcast_w, const float* __restrict__ bcast_b,
    const float* __restrict__ wln_g, const float* __restrict__ wln_b,
    const float* __restrict__ cq_w, const float* __restrict__ cq_b,
    const float* __restrict__ ck_w, const float* __restrict__ ck_b,
    const float* __restrict__ cv_w, const float* __restrict__ cv_b,
    const float* __restrict__ co_w, const float* __restrict__ co_b,
    const float* __restrict__ cln_g, const float* __restrict__ cln_b,
    const float* __restrict__ P_w, const float* __restrict__ P_b,
    const float* __restrict__ D1_w, const float* __restrict__ D1_b,
    const float* __restrict__ D2_w, const float* __restrict__ D2_b,
    const float* __restrict__ G_w, const float* __restrict__ G_b,
    const float* __restrict__ SM_w, const float* __restrict__ SM_b,
    const float* __restrict__ PR_w, const float* __restrict__ PR_b,
    const float* __restrict__ ln_g, const float* __restrict__ ln_b,
    float* __restrict__ states, float* __restrict__ prediction,
    float* __restrict__ states2, float* __restrict__ bcastv,
    float* __restrict__ Qg, float* __restrict__ Kg, float* __restrict__ Vg,
    __hip_bfloat16* __restrict__ projbf)
{
    const int blk = blockIdx.x, tid = threadIdx.x;
    __shared__ SwarmSh sh;

    // init: zero states (32768) + prediction (32768); contiguous in ws
    {
        int i = blk*1024 + tid;          // 64*1024 == 65536 exactly
        states[i] = 0.f;                 // prediction == states + 32768
    }
    gbar(bar);

    for (int c = 0; c < NCHUNK; c++){
        // ================= phase 1: timestep scan (blocks 0..7, one per b) =================
        if (blk < B_){
            const int b = blk;
            const int d = tid >> 3, kq = tid & 7;
            const int lane = tid & 63, wv = tid >> 6;
            const int tbase = b*T_ + c*CH_;
            for (int i = tid; i < N_*D_; i += 1024){
                int n = i >> 7, dd = i & 127;
                sh.s.stS[n*STP + dd] = states[(b*N_ + n)*D_ + dd];
            }
            __syncthreads();
            // register preloads (weights constant across steps)
            float4 wr0,wr1,wr2,wr3, or0,or1,or2,or3;
            {
                const float4* p = (const float4*)(sgwT + d*D_ + kq*16);
                wr0=p[0]; wr1=p[1]; wr2=p[2]; wr3=p[3];
                const float4* q = (const float4*)(outT + d*D_ + kq*16);
                or0=q[0]; or1=q[1]; or2=q[2]; or3=q[3];
            }
            float sgp[8], svp[8], orr[8];
            #pragma unroll
            for (int st = 0; st < CH_; st++){
                sgp[st] = sg_sens[((size_t)(tbase+st)*S_ + kq)*D_ + d];
                svp[st] = sensory[((size_t)(tbase+st)*S_ + kq)*D_ + d];
                orr[st] = outres[(size_t)(tbase+st)*D_ + d];
            }
            float sgb = sgate_b[d], salw_r = sal_w[d], outb_r = out_b[d], salb0 = sal_b[0];

            // ---- per-chunk frozen-node (8..31) softmax precompute ----
            {
                float sf[3];
                #pragma unroll
                for (int nb = 0; nb < 3; nb++){
                    sf[nb] = sh.s.stS[(8 + nb*8 + kq)*STP + d] * salw_r;
                    sf[nb] += __shfl_xor(sf[nb], 8, 64);
                    sf[nb] += __shfl_xor(sf[nb], 16, 64);
                    sf[nb] += __shfl_xor(sf[nb], 32, 64);
                }
                if ((lane >> 3) == 0){
                    #pragma unroll
                    for (int nb = 0; nb < 3; nb++) sh.s.sfp[wv*24 + nb*8 + kq] = sf[nb];
                }
            }
            __syncthreads();
            if (tid < 24){
                float s = 0.f;
                for (int w = 0; w < 16; w++) s += sh.s.sfp[w*24 + tid];
                sh.s.efx[tid] = 5.f*(s + salb0);   // v5 temporarily
            }
            __syncthreads();
            if (tid < 32){
                float v = (tid < 24) ? sh.s.efx[tid] : -3.0e38f;
                float m = v;
                m = fmaxf(m, __shfl_xor(m, 1, 32));
                m = fmaxf(m, __shfl_xor(m, 2, 32));
                m = fmaxf(m, __shfl_xor(m, 4, 32));
                m = fmaxf(m, __shfl_xor(m, 8, 32));
                m = fmaxf(m, __shfl_xor(m, 16, 32));
                float e = (tid < 24) ? expf(v - m) : 0.f;
                float Z = e;
                Z += __shfl_xor(Z, 1, 32); Z += __shfl_xor(Z, 2, 32);
                Z += __shfl_xor(Z, 4, 32); Z += __shfl_xor(Z, 8, 32);
                Z += __shfl_xor(Z, 16, 32);
                if (tid < 24) sh.s.efx[tid] = e;
                if (tid == 0){ sh.s.Kf5 = m; sh.s.Zf = Z; }
            }
            __syncthreads();
            {
                float up = 0.f;
                #pragma unroll
                for (int nb = 0; nb < 3; nb++)
                    up += sh.s.efx[nb*8 + kq] * sh.s.stS[(8 + nb*8 + kq)*STP + d];
                up += __shfl_xor(up, 1, 64);
                up += __shfl_xor(up, 2, 64);
                up += __shfl_xor(up, 4, 64);
                if (kq == 0) sh.s.U[d] = up;
            }
            float Kf5 = sh.s.Kf5, Zf = sh.s.Zf;
            __syncthreads();

            // ---- 8 sequential timesteps ----
            for (int step = 0; step < CH_; step++){
                // sgate partials for all 8 live nodes (k-range kq*16..+15 in regs)
                float ps[8];
                #pragma unroll
                for (int s = 0; s < 8; s++){
                    const float4* sp = (const float4*)(sh.s.stS + s*STP + kq*16);
                    float4 v0 = sp[0], v1 = sp[1], v2 = sp[2], v3 = sp[3];
                    ps[s] = v0.x*wr0.x + v0.y*wr0.y + v0.z*wr0.z + v0.w*wr0.w
                          + v1.x*wr1.x + v1.y*wr1.y + v1.z*wr1.z + v1.w*wr1.w
                          + v2.x*wr2.x + v2.y*wr2.y + v2.z*wr2.z + v2.w*wr2.w
                          + v3.x*wr3.x + v3.y*wr3.y + v3.z*wr3.z + v3.w*wr3.w;
                }
                #pragma unroll
                for (int s = 0; s < 8; s++){
                    ps[s] += __shfl_xor(ps[s], 1, 64);
                    ps[s] += __shfl_xor(ps[s], 2, 64);
                    ps[s] += __shfl_xor(ps[s], 4, 64);
                }
                float dot = 0.f;
                #pragma unroll
                for (int s = 0; s < 8; s++) if (kq == s) dot = ps[s];
                float cur = sh.s.stS[kq*STP + d];
                float sg = sigm(dot + sgp[step] + sgb);
                float ns = sg*cur + (1.f - sg)*svp[step];
                __syncthreads();
                sh.s.stS[kq*STP + d] = ns;
                // sal for live node s=kq
                float sp_ = ns * salw_r;
                sp_ += __shfl_xor(sp_, 8, 64);
                sp_ += __shfl_xor(sp_, 16, 64);
                sp_ += __shfl_xor(sp_, 32, 64);
                if ((lane >> 3) == 0) sh.s.salp[wv*8 + kq] = sp_;
                __syncthreads();
                if (tid < 64){
                    int s8 = tid & 7, w8 = tid >> 3;
                    float v = sh.s.salp[w8*8 + s8] + sh.s.salp[(w8 + 8)*8 + s8];
                    v += __shfl_xor(v, 8, 64);
                    v += __shfl_xor(v, 16, 64);
                    v += __shfl_xor(v, 32, 64);
                    float v5 = 5.f*(v + salb0);
                    float mx = v5;
                    mx = fmaxf(mx, __shfl_xor(mx, 1, 64));
                    mx = fmaxf(mx, __shfl_xor(mx, 2, 64));
                    mx = fmaxf(mx, __shfl_xor(mx, 4, 64));
                    mx = fmaxf(mx, Kf5);
                    float e = expf(v5 - mx);
                    float Es = e;
                    Es += __shfl_xor(Es, 1, 64);
                    Es += __shfl_xor(Es, 2, 64);
                    Es += __shfl_xor(Es, 4, 64);
                    float fE = expf(Kf5 - mx);
                    float Z = Es + fE*Zf;
                    if (w8 == 0){
                        sh.s.esv[s8] = e / Z;
                        if (s8 == 0) sh.s.ffix = fE / Z;
                    }
                }
                __syncthreads();
                // workspace
                float wp = sh.s.esv[kq] * ns;
                wp += __shfl_xor(wp, 1, 64);
                wp += __shfl_xor(wp, 2, 64);
                wp += __shfl_xor(wp, 4, 64);
                if (kq == 0) sh.s.wsp[d] = wp + sh.s.ffix * sh.s.U[d];
                __syncthreads();
                // out-projection (workspace half; residual half precomputed in orr)
                {
                    const float4* w4 = (const float4*)(sh.s.wsp + kq*16);
                    float4 a0 = w4[0], a1 = w4[1], a2 = w4[2], a3 = w4[3];
                    float op = a0.x*or0.x + a0.y*or0.y + a0.z*or0.z + a0.w*or0.w
                             + a1.x*or1.x + a1.y*or1.y + a1.z*or1.z + a1.w*or1.w
                             + a2.x*or2.x + a2.y*or2.y + a2.z*or2.z + a2.w*or2.w
                             + a3.x*or3.x + a3.y*or3.y + a3.z*or3.z + a3.w*or3.w;
                    op += __shfl_xor(op, 1, 64);
                    op += __shfl_xor(op, 2, 64);
                    op += __shfl_xor(op, 4, 64);
                    if (kq == 0)
                        projbf[(size_t)(tbase + step)*D_ + d] =
                            __float2bfloat16(gelu_f(op + orr[step] + outb_r));
                }
                if (step == CH_ - 1){
                    // bcast = LN(workspace @ bcast_w + b)
                    float bp = 0.f;
                    #pragma unroll
                    for (int j = 0; j < 16; j++)
                        bp += sh.s.wsp[kq*16 + j] * bcast_w[(kq*16 + j)*D_ + d];
                    bp += __shfl_xor(bp, 1, 64);
                    bp += __shfl_xor(bp, 2, 64);
                    bp += __shfl_xor(bp, 4, 64);
                    if (kq == 0) sh.s.bcd[d] = bp + bcast_b[d];
                    states[(b*N_ + kq)*D_ + d] = ns;   // final live-node states
                    __syncthreads();
                    if (tid < 64){
                        float x0 = sh.s.bcd[tid], x1 = sh.s.bcd[tid + 64];
                        float sm = x0 + x1;
                        sm += __shfl_xor(sm, 1, 64); sm += __shfl_xor(sm, 2, 64);
                        sm += __shfl_xor(sm, 4, 64); sm += __shfl_xor(sm, 8, 64);
                        sm += __shfl_xor(sm, 16, 64); sm += __shfl_xor(sm, 32, 64);
                        float mean = sm*(1.f/128.f);
                        float d0 = x0 - mean, d1 = x1 - mean;
                        float vs = d0*d0 + d1*d1;
                        vs += __shfl_xor(vs, 1, 64); vs += __shfl_xor(vs, 2, 64);
                        vs += __shfl_xor(vs, 4, 64); vs += __shfl_xor(vs, 8, 64);
                        vs += __shfl_xor(vs, 16, 64); vs += __shfl_xor(vs, 32, 64);
                        float inv = 1.f/sqrtf(vs*(1.f/128.f) + 1e-5f);
                        bcastv[b*D_ + tid]      = d0*inv*wln_g[tid] + wln_b[tid];
                        bcastv[b*D_ + tid + 64] = d1*inv*wln_g[tid+64] + wln_b[tid+64];
                    }
                }
                __syncthreads();
            }
        }
        gbar(bar);

        // ================= phase 2: QKV (4 (b,n) pairs per block, same b) =================
        {
            const int b = blk >> 3, g = blk & 7;
            const int pi = tid >> 8, t = tid & 255, d = t & 127, h = t >> 7;
            const int n = g*4 + pi;
            if (t < 128) sh.q.srow[pi][t] = states[(b*N_ + n)*D_ + t];
            __syncthreads();
            const float* Ws[3] = {cq_w, ck_w, cv_w};
            const float* bs[3] = {cq_b, ck_b, cv_b};
            float* dst[3] = {Qg, Kg, Vg};
            for (int m = 0; m < 3; m++){
                float a = 0.f;
                #pragma unroll 8
                for (int k = 0; k < 64; k++) a += sh.q.srow[pi][h*64 + k] * Ws[m][(h*64 + k)*D_ + d];
                sh.q.part[pi][h][d] = a;
                __syncthreads();
                if (h == 0) dst[m][(b*N_ + n)*D_ + d] = sh.q.part[pi][0][d] + sh.q.part[pi][1][d] + bs[m][d];
                __syncthreads();
            }
        }
        gbar(bar);

        // ================= phase 3: comm attention + co + LN =================
        {
            const int b = blk >> 3, g = blk & 7;
            const int pi = tid >> 8, t = tid & 255, d = t & 127, h = t >> 7;
            const int n = g*4 + pi;
            for (int i = tid; i < N_*D_; i += 1024){
                int r = i >> 7, dd = i & 127;
                sh.a.Kt[r*KSP + dd] = Kg[(b*N_ + r)*D_ + dd];
                sh.a.Vt[r*KSP + dd] = Vg[(b*N_ + r)*D_ + dd];
            }
            if (t < 128) sh.a.q[pi][t] = Qg[(b*N_ + n)*D_ + t];
            __syncthreads();
            if (t < 128){
                int hh = t >> 5, m = t & 31;
                float s = 0.f;
                #pragma unroll 8
                for (int j = 0; j < 32; j++) s += sh.a.q[pi][hh*32 + j] * sh.a.Kt[m*KSP + hh*32 + j];
                s *= 0.17677669529663687f;
                float mx = s;
                mx = fmaxf(mx, __shfl_xor(mx, 1, 32));
                mx = fmaxf(mx, __shfl_xor(mx, 2, 32));
                mx = fmaxf(mx, __shfl_xor(mx, 4, 32));
                mx = fmaxf(mx, __shfl_xor(mx, 8, 32));
                mx = fmaxf(mx, __shfl_xor(mx, 16, 32));
                float e = expf(s - mx);
                float Z = e;
                Z += __shfl_xor(Z, 1, 32); Z += __shfl_xor(Z, 2, 32);
                Z += __shfl_xor(Z, 4, 32); Z += __shfl_xor(Z, 8, 32);
                Z += __shfl_xor(Z, 16, 32);
                sh.a.attw[pi][hh][m] = e / Z;
            }
            __syncthreads();
            if (t < 128){
                int hh = t >> 5;
                float mm = 0.f;
                #pragma unroll 8
                for (int m = 0; m < 32; m++) mm += sh.a.attw[pi][hh][m] * sh.a.Vt[m*KSP + t];
                sh.a.msg[pi][t] = mm;
            }
            __syncthreads();
            float a = 0.f;
            #pragma unroll 8
            for (int k = 0; k < 64; k++) a += sh.a.msg[pi][h*64 + k] * co_w[(h*64 + k)*D_ + d];
            sh.a.part[pi][h][d] = a;
            __syncthreads();
            float x = 0.f;
            if (h == 0) x = states[(b*N_ + n)*D_ + d] + sh.a.part[pi][0][d] + sh.a.part[pi][1][d] + co_b[d];
            float sm = (h == 0) ? x : 0.f;
            sm += __shfl_xor(sm, 1, 64); sm += __shfl_xor(sm, 2, 64);
            sm += __shfl_xor(sm, 4, 64); sm += __shfl_xor(sm, 8, 64);
            sm += __shfl_xor(sm, 16, 64); sm += __shfl_xor(sm, 32, 64);
            if ((t & 63) == 0) sh.a.red[pi][t >> 6] = sm;
            __syncthreads();
            float mean = (sh.a.red[pi][0] + sh.a.red[pi][1] + sh.a.red[pi][2] + sh.a.red[pi][3])*(1.f/128.f);
            float dv = x - mean;
            float vs = (h == 0) ? dv*dv : 0.f;
            vs += __shfl_xor(vs, 1, 64); vs += __shfl_xor(vs, 2, 64);
            vs += __shfl_xor(vs, 4, 64); vs += __shfl_xor(vs, 8, 64);
            vs += __shfl_xor(vs, 16, 64); vs += __shfl_xor(vs, 32, 64);
            __syncthreads();
            if ((t & 63) == 0) sh.a.red[pi][t >> 6] = vs;
            __syncthreads();
            float var = (sh.a.red[pi][0] + sh.a.red[pi][1] + sh.a.red[pi][2] + sh.a.red[pi][3])*(1.f/128.f);
            if (h == 0)
                states2[(b*N_ + n)*D_ + d] = dv*(1.f/sqrtf(var + 1e-5f))*cln_g[d] + cln_b[d];
        }
        gbar(bar);

        // ================= phase 4: per-node brains (same n per block, 4 b's) =================
        {
            const int n = blk >> 1, half = blk & 1;
            const int pi = tid >> 8, t = tid & 255, d = t & 127, h = t >> 7;
            const int b = half*4 + pi;
            float inc_p = 0.f;
            for (int m = h*16; m < h*16 + 16; m++) inc_p += states2[(b*N_ + m)*D_ + d];
            sh.b.part[pi][h][d] = inc_p;
            if (h == 0) sh.b.strow[pi][d] = states2[(b*N_ + n)*D_ + d];
            __syncthreads();
            float inc = (sh.b.part[pi][0][d] + sh.b.part[pi][1][d])*(1.0f/N_);
            float pr = prediction[(b*N_ + n)*D_ + d];
            float diff = inc - pr;
            sh.b.red[pi][t] = (h == 0) ? diff*diff : 0.f;
            __syncthreads();
            for (int s2 = 128; s2; s2 >>= 1){ if (t < s2) sh.b.red[pi][t] += sh.b.red[pi][t + s2]; __syncthreads(); }
            float pe = sh.b.red[pi][0]*(1.0f/D_);
            float surprise = (c > 0) ? sigm(pe*10.0f) : 0.0f;
            float scale = 1.0f + 0.5f*surprise;
            __syncthreads();
            if (h == 0){
                sh.b.pin[pi][d]        = inc*scale;
                sh.b.pin[pi][D_ + d]   = bcastv[b*D_ + d];
                sh.b.pin[pi][2*D_ + d] = sh.b.strow[pi][d];
            }
            __syncthreads();
            // P
            {
                const float* Wn = P_w + ((size_t)n*384 + h*192)*D_ + d;
                float a = 0.f;
                #pragma unroll 4
                for (int k = 0; k < 192; k++) a += sh.b.pin[pi][h*192 + k]*Wn[(size_t)k*D_];
                sh.b.part[pi][h][d] = a;
                __syncthreads();
                if (h == 0) sh.b.din[pi][d] = gelu_f(sh.b.part[pi][0][d] + sh.b.part[pi][1][d] + P_b[n*D_ + d]);
                __syncthreads();
            }
            // SM
            {
                const float* Wn = SM_w + ((size_t)n*128 + h*64)*D_ + d;
                float a = 0.f;
                #pragma unroll 4
                for (int k = 0; k < 64; k++) a += sh.b.strow[pi][h*64 + k]*Wn[(size_t)k*D_];
                sh.b.part[pi][h][d] = a;
                __syncthreads();
                if (h == 0) sh.b.din[pi][D_ + d] = sh.b.part[pi][0][d] + sh.b.part[pi][1][d] + SM_b[n*D_ + d];
                __syncthreads();
            }
            // D1 -> pin[0:128]
            {
                const float* Wn = D1_w + ((size_t)n*256 + h*128)*D_ + d;
                float a = 0.f;
                #pragma unroll 4
                for (int k = 0; k < 128; k++) a += sh.b.din[pi][h*128 + k]*Wn[(size_t)k*D_];
                sh.b.part[pi][h][d] = a;
                __syncthreads();
                if (h == 0) sh.b.pin[pi][d] = gelu_f(sh.b.part[pi][0][d] + sh.b.part[pi][1][d] + D1_b[n*D_ + d]);
                __syncthreads();
            }
            // D2
            {
                const float* Wn = D2_w + ((size_t)n*128 + h*64)*D_ + d;
                float a = 0.f;
                #pragma unroll 4
                for (int k = 0; k < 64; k++) a += sh.b.pin[pi][h*64 + k]*Wn[(size_t)k*D_];
                sh.b.part[pi][h][d] = a;
                __syncthreads();
                if (h == 0){
                    float v = sh.b.part[pi][0][d] + sh.b.part[pi][1][d] + D2_b[n*D_ + d];
                    sh.b.dec[pi][d] = v;
                    sh.b.gin[pi][d] = sh.b.strow[pi][d];
                    sh.b.gin[pi][D_ + d] = v;
                }
                __syncthreads();
            }
            // G
            {
                const float* Wn = G_w + ((size_t)n*256 + h*128)*D_ + d;
                float a = 0.f;
                #pragma unroll 4
                for (int k = 0; k < 128; k++) a += sh.b.gin[pi][h*128 + k]*Wn[(size_t)k*D_];
                sh.b.part[pi][h][d] = a;
                __syncthreads();
            }
            float g_ = 0.f, pre = 0.f;
            if (h == 0){
                g_ = sigm(sh.b.part[pi][0][d] + sh.b.part[pi][1][d] + G_b[n*D_ + d]);
                pre = g_*sh.b.dec[pi][d] + (1.0f - g_)*sh.b.strow[pi][d];
            }
            sh.b.red[pi][t] = (h == 0) ? pre : 0.f;
            __syncthreads();
            for (int s2 = 128; s2; s2 >>= 1){ if (t < s2) sh.b.red[pi][t] += sh.b.red[pi][t + s2]; __syncthreads(); }
            float mn = sh.b.red[pi][0]*(1.0f/D_);
            __syncthreads();
            float dv2 = pre - mn;
            sh.b.red[pi][t] = (h == 0) ? dv2*dv2 : 0.f;
            __syncthreads();
            for (int s2 = 128; s2; s2 >>= 1){ if (t < s2) sh.b.red[pi][t] += sh.b.red[pi][t + s2]; __syncthreads(); }
            float var = sh.b.red[pi][0]*(1.0f/D_);
            __syncthreads();
            if (h == 0){
                float nv = dv2*(1.0f/sqrtf(var + 1e-5f))*ln_g[d] + ln_b[d];
                sh.b.dec[pi][d] = nv;      // reuse dec as new_states staging
                states[(b*N_ + n)*D_ + d] = nv;
            }
            __syncthreads();
            // PR
            {
                const float* Wn = PR_w + ((size_t)n*128 + h*64)*D_ + d;
                float a = 0.f;
                #pragma unroll 4
                for (int k = 0; k < 64; k++) a += sh.b.dec[pi][h*64 + k]*Wn[(size_t)k*D_];
                sh.b.part[pi][h][d] = a;
                __syncthreads();
                if (h == 0) prediction[(b*N_ + n)*D_ + d] = sh.b.part[pi][0][d] + sh.b.part[pi][1][d] + PR_b[n*D_ + d];
            }
        }
        gbar(bar);
    }
}

// -------------------- f32 -> bf16 --------------------
__global__ void k_tobf16(const float* __restrict__ src, __hip_bfloat16* __restrict__ dst, int nelem){
    int i = blockIdx.x*256 + threadIdx.x;
    int stride = gridDim.x*256;
    for (; i < nelem; i += stride) dst[i] = __float2bfloat16(src[i]);
}

// -------------------- final logits GEMM: (2048x128) @ (128x32000) + bias --------------------
typedef __attribute__((ext_vector_type(8))) short short8;
typedef __attribute__((ext_vector_type(4))) float f32x4;

__global__ void __launch_bounds__(256) k_gemm(const __hip_bfloat16* __restrict__ A,
                       const __hip_bfloat16* __restrict__ Bv,
                       const float* __restrict__ out_bias,
                       float* __restrict__ out){
    int vblk = blockIdx.x;   // 125 blocks * 256 v
    int mblk = blockIdx.y;   // 32 blocks * 64 m
    int tid = threadIdx.x;
    int wave = tid >> 6, lane = tid & 63;
    int l16 = lane & 15, quad = lane >> 4;
    int mrow = mblk*64 + wave*16 + l16;
    f32x4 acc[16];
    #pragma unroll
    for (int j = 0; j < 16; j++){ f32x4 z = {0.f,0.f,0.f,0.f}; acc[j] = z; }
    short8 afr[4];
    const short* Ap = reinterpret_cast<const short*>(A);
    #pragma unroll
    for (int ks = 0; ks < 4; ks++)
        afr[ks] = *reinterpret_cast<const short8*>(Ap + mrow*128 + ks*32 + quad*8);
    const short* Bp = reinterpret_cast<const short*>(Bv);
    int vcolbase = vblk*256;
    #pragma unroll
    for (int jj = 0; jj < 16; jj++){
        int v = vcolbase + jj*16 + l16;
        #pragma unroll
        for (int ks = 0; ks < 4; ks++){
            short8 bfr = *reinterpret_cast<const short8*>(Bp + (size_t)v*128 + ks*32 + quad*8);
            acc[jj] = __builtin_amdgcn_mfma_f32_16x16x32_bf16(afr[ks], bfr, acc[jj], 0,0,0);
        }
    }
    int mbase = mblk*64 + wave*16 + quad*4;
    #pragma unroll
    for (int jj = 0; jj < 16; jj++){
        int v = vcolbase + jj*16 + l16;
        float bias = out_bias[v];
        #pragma unroll
        for (int r = 0; r < 4; r++){
            out[(size_t)(mbase + r)*V_ + v] = acc[jj][r] + bias;
        }
    }
}

extern "C" void kernel_launch(void* const* d_in, const int* in_sizes, int n_in,
                              void* d_out, int out_size, void* d_ws, size_t ws_size,
                              hipStream_t stream){
    (void)in_sizes; (void)n_in; (void)out_size; (void)ws_size;
    const int*   idx      = (const int*)  d_in[0];
    const float* emb      = (const float*)d_in[1];
    const float* pos_emb  = (const float*)d_in[2];
    const float* ifc_w    = (const float*)d_in[3];
    const float* ifc_b    = (const float*)d_in[4];
    const float* ifc_g    = (const float*)d_in[5];
    const float* ifc_beta = (const float*)d_in[6];
    const float* sproj_w  = (const float*)d_in[7];
    const float* sproj_b  = (const float*)d_in[8];
    const float* sgate_w  = (const float*)d_in[9];
    const float* sgate_b  = (const float*)d_in[10];
    const float* P_w  = (const float*)d_in[11];
    const float* P_b  = (const float*)d_in[12];
    const float* D1_w = (const float*)d_in[13];
    const float* D1_b = (const float*)d_in[14];
    const float* D2_w = (const float*)d_in[15];
    const float* D2_b = (const float*)d_in[16];
    // d_in[17], d_in[18]: A_w, A_b -- unused by the reference output
    const float* G_w  = (const float*)d_in[19];
    const float* G_b  = (const float*)d_in[20];
    const float* SM_w = (const float*)d_in[21];
    const float* SM_b = (const float*)d_in[22];
    const float* PR_w = (const float*)d_in[23];
    const float* PR_b = (const float*)d_in[24];
    const float* cq_w = (const float*)d_in[25];
    const float* cq_b = (const float*)d_in[26];
    const float* ck_w = (const float*)d_in[27];
    const float* ck_b = (const float*)d_in[28];
    const float* cv_w = (const float*)d_in[29];
    const float* cv_b = (const float*)d_in[30];
    const float* co_w = (const float*)d_in[31];
    const float* co_b = (const float*)d_in[32];
    const float* cln_g = (const float*)d_in[33];
    const float* cln_b = (const float*)d_in[34];
    const float* sal_w = (const float*)d_in[35];
    const float* sal_b = (const float*)d_in[36];
    const float* bcast_w = (const float*)d_in[37];
    const float* bcast_b = (const float*)d_in[38];
    const float* wln_g = (const float*)d_in[39];
    const float* wln_b = (const float*)d_in[40];
    const float* res_w = (const float*)d_in[41];
    const float* res_b = (const float*)d_in[42];
    const float* out_w = (const float*)d_in[43];
    const float* out_b = (const float*)d_in[44];
    const float* out_bias = (const float*)d_in[45];
    const float* ln_g = (const float*)d_in[46];
    const float* ln_b = (const float*)d_in[47];

    float* ws = (float*)d_ws;
    unsigned* bar     = (unsigned*)ws;              // 16 floats reserved
    float* states     = ws + 16;                    // 32768
    float* prediction = ws + 16 + 32768;            // 32768 (contiguous with states)
    float* states2    = ws + 16 + 65536;            // 32768
    float* bcastv     = ws + 16 + 98304;            // 1024
    float* Qg         = ws + 16 + 99328;            // 32768
    float* Kg         = ws + 16 + 132096;           // 32768
    float* Vg         = ws + 16 + 164864;           // 32768
    float* percepts   = ws + 16 + 197632;           // 262144
    float* sensory    = ws + 16 + 459776;           // 2097152
    float* sg_sens    = ws + 16 + 2556928;          // 2097152
    float* outres     = ws + 16 + 4654080;          // 262144
    float* sgwT       = ws + 16 + 4916224;          // 16384
    float* outT       = ws + 16 + 4932608;          // 16384
    __hip_bfloat16* projbf = (__hip_bfloat16*)(ws + 16 + 4948992);          // 262144 bf16
    __hip_bfloat16* emb_bf = (__hip_bfloat16*)(ws + 16 + 4948992 + 131072); // 4096000 bf16; ends ~28.5 MB

    hipMemsetAsync(bar, 0, 64, stream);
    k_tobf16<<<512,256,0,stream>>>(emb, emb_bf, V_*D_);
    k_percepts<<<B_*T_,128,0,stream>>>(idx, emb, pos_emb, ifc_w, ifc_b, ifc_g, ifc_beta, percepts);
    k_precomp<<<256,256,0,stream>>>(percepts, sproj_w, sproj_b, sgate_w, res_w, res_b, out_w,
                                    sensory, sg_sens, outres);
    k_transp<<<128,128,0,stream>>>(sgate_w, out_w, sgwT, outT);
    k_swarm<<<NBLK,1024,0,stream>>>(bar, sensory, sg_sens, sgwT, outT, sgate_b, sal_w, sal_b,
                                    out_b, outres, bcast_w, bcast_b, wln_g, wln_b,
                                    cq_w, cq_b, ck_w, ck_b, cv_w, cv_b, co_w, co_b, cln_g, cln_b,
                                    P_w, P_b, D1_w, D1_b, D2_w, D2_b, G_w, G_b,
                                    SM_w, SM_b, PR_w, PR_b, ln_g, ln_b,
                                    states, prediction, states2, bcastv, Qg, Kg, Vg, projbf);
    k_gemm<<<dim3(125,32),256,0,stream>>>(projbf, emb_bf, out_bias, (float*)d_out);
}